// Round 16
// baseline (56.644 us; speedup 1.0000x reference)
//
#include <hip/hip_runtime.h>
#include <hip/hip_bf16.h>
#include <hip/hip_fp16.h>

// GaussianSmoothing (2,1,192,192,192) f32, separable K=13 sigma=2.
// R16 = R13 + nontemporal LOADS of x in blur_w (x is single-use; avoid
// allocating 57 MB of dead lines in L2/L3, protect tmp1 residency for colH).
// Pass 1 blur_w : W-blur, 2 quads/thread, NT f32 loads -> f16 tmp1
// Pass 2 colH   : H direct-form, CH=12, f16 tmp1 -> f16 tmp2
// Pass 3 colD   : D direct-form, CH=12, NT f32 stores, f16 tmp2 -> f32 d_out

#define DIM 192
#define DIM2 (192 * 192)
#define NIMG 2
#define TOTAL (NIMG * DIM * DIM2)   // 14,155,776 floats
#define NQ (TOTAL / 4)              // 3,538,944 quads (4 elems, 48/row)
#define NPAIR (NQ / 2)              // 1,769,472 quad-pairs (24/row)

typedef float f32x4 __attribute__((ext_vector_type(4)));

#define GTAPS                                                     \
    constexpr float G[13] = {                                     \
        2.2159242e-03f, 8.7641505e-03f, 2.6995483e-02f,           \
        6.4758800e-02f, 1.2098536e-01f, 1.7603266e-01f,           \
        1.9947114e-01f, 1.7603266e-01f, 1.2098536e-01f,           \
        6.4758800e-02f, 2.6995483e-02f, 8.7641505e-03f,           \
        2.2159242e-03f };

// ---- f16 helpers ----------------------------------------------------------
__device__ __forceinline__ float4 ld_h4(const uint2* __restrict__ p) {
    uint2 u = *p;
    __half2 h0 = *(__half2*)&u.x;
    __half2 h1 = *(__half2*)&u.y;
    return make_float4(__low2float(h0), __high2float(h0),
                       __low2float(h1), __high2float(h1));
}
__device__ __forceinline__ uint2 st_h4(float4 v) {
    __half2 h0 = __floats2half2_rn(v.x, v.y);
    __half2 h1 = __floats2half2_rn(v.z, v.w);
    uint2 u;
    u.x = *(unsigned*)&h0;
    u.y = *(unsigned*)&h1;
    return u;
}

// ---------------------------------------------------------------------------
// Pass 1: W-blur, TWO quads (8 floats) per thread. Window = 6 quads
// [2jp-2 .. 2jp+3], clamped + 0/1-masked (branch-free). Input loads are
// NONTEMPORAL (single-use stream). One 16B uint4 store of 8 f16 values.
// Grid = NPAIR/256 = 6912 blocks (13824 waves — wave count proven critical).
// ---------------------------------------------------------------------------
__global__ __launch_bounds__(256) void blur_w(const float* __restrict__ in,
                                              uint4* __restrict__ out) {
    GTAPS
    const int j = blockIdx.x * 256 + threadIdx.x;   // pair id
    const int jp = j % 24;                          // pair within row
    const int rowq = (j / 24) * 48;                 // row base, quad units

    float f[24];
#pragma unroll
    for (int d = 0; d < 6; ++d) {
        int qq = 2 * jp - 2 + d;
        const float m = (qq >= 0 && qq < 48) ? 1.0f : 0.0f;
        qq = min(max(qq, 0), 47);
        f32x4 v = __builtin_nontemporal_load((const f32x4*)(in) + rowq + qq);
        if (d < 2 || d > 3) {                       // d=2,3 always valid
            v.x *= m; v.y *= m; v.z *= m; v.w *= m;
        }
        f[d * 4 + 0] = v.x; f[d * 4 + 1] = v.y;
        f[d * 4 + 2] = v.z; f[d * 4 + 3] = v.w;
    }

    float o[8];
#pragma unroll
    for (int t = 0; t < 8; ++t) {
        float a = 0.0f;
#pragma unroll
        for (int k = 0; k < 13; ++k) a += G[k] * f[t + 2 + k];
        o[t] = a;
    }
    uint2 lo = st_h4(make_float4(o[0], o[1], o[2], o[3]));
    uint2 hi = st_h4(make_float4(o[4], o[5], o[6], o[7]));
    uint4 r; r.x = lo.x; r.y = lo.y; r.z = hi.x; r.w = hi.y;
    out[j] = r;
}

// ---------------------------------------------------------------------------
// Passes 2/3: DIRECT-FORM axis blur (R13-proven). Thread owns one f16-quad
// column (uint2), loads all CH+12=24 inputs upfront (deep MLP), then computes
// CH=12 outputs at 13 FMA/output. Edge chunks compile-time clipped.
//   column c: base = (c / Q) * M + (c % Q)   (quad units)
//   H: Q=48, M=9216, S=48     D: Q=9216, M=1769472, S=9216
// ncols = 18432; chunks = 16; block = 128 -> grid = 2304 (4608 waves).
// OUT_F32 (final pass) stores are NONTEMPORAL.
// ---------------------------------------------------------------------------
#define CH 12
#define NSTEP (CH + 12)     // 24
#define NCHUNK (DIM / CH)   // 16

template <int S, bool OUT_F32, int CLIP>
__device__ __forceinline__ void col_body(const uint2* __restrict__ in,
                                         void* __restrict__ out_,
                                         int base, int d0) {
    GTAPS
    float4 v[NSTEP];
#pragma unroll
    for (int s = 0; s < NSTEP; ++s) {
        bool valid = true;
        if (CLIP < 0) valid = (s >= 6);          // d0 == 0:   i = s-6
        if (CLIP > 0) valid = (s < NSTEP - 6);   // d0 == 180: i = 174+s
        if (valid) v[s] = ld_h4(&in[base + (d0 - 6 + s) * S]);
        else       v[s] = make_float4(0.f, 0.f, 0.f, 0.f);
    }
#pragma unroll
    for (int t = 0; t < CH; ++t) {
        float4 a = make_float4(0.f, 0.f, 0.f, 0.f);
#pragma unroll
        for (int k = 0; k < 13; ++k) {
            const float g = G[k];
            a.x += g * v[t + k].x;
            a.y += g * v[t + k].y;
            a.z += g * v[t + k].z;
            a.w += g * v[t + k].w;
        }
        const int o = base + (d0 + t) * S;
        if (OUT_F32) {
            f32x4 av;
            av.x = a.x; av.y = a.y; av.z = a.z; av.w = a.w;
            __builtin_nontemporal_store(av, &((f32x4*)out_)[o]);
        } else {
            ((uint2*)out_)[o] = st_h4(a);
        }
    }
}

template <int Q, int M, int S, bool OUT_F32>
__global__ __launch_bounds__(128) void col_blur(const uint2* __restrict__ in,
                                                void* __restrict__ out_) {
    const int gt = blockIdx.x * 128 + threadIdx.x;
    const int chunk = gt / 18432;          // block-uniform (18432 % 128 == 0)
    const int c = gt % 18432;
    const int base = (c / Q) * M + (c % Q);
    const int d0 = chunk * CH;

    if (chunk == 0)                col_body<S, OUT_F32, -1>(in, out_, base, d0);
    else if (chunk == NCHUNK - 1)  col_body<S, OUT_F32, +1>(in, out_, base, d0);
    else                           col_body<S, OUT_F32,  0>(in, out_, base, d0);
}

extern "C" void kernel_launch(void* const* d_in, const int* in_sizes, int n_in,
                              void* d_out, int out_size, void* d_ws, size_t ws_size,
                              hipStream_t stream) {
    const float* x = (const float*)d_in[0];
    float* out = (float*)d_out;
    uint2* tmp1 = (uint2*)d_ws;               // f16, 28.3 MB (NQ uint2)
    uint2* tmp2 = ((uint2*)d_ws) + NQ;        // f16, 28.3 MB

    // Pass 1: W one-shot (2 quads/thread), NT f32 loads -> f16 tmp1
    blur_w<<<NPAIR / 256, 256, 0, stream>>>(x, (uint4*)tmp1);
    // Pass 2: H axis (stride 48 quads), f16 -> f16, direct form
    col_blur<48, 9216, 48, false><<<2304, 128, 0, stream>>>(tmp1, (void*)tmp2);
    // Pass 3: D axis (stride 9216 quads), f16 -> f32 out, direct form, NT stores
    col_blur<9216, 1769472, 9216, true><<<2304, 128, 0, stream>>>(tmp2, (void*)out);
}

// Round 17
// 42.506 us; speedup vs baseline: 1.3326x; 1.3326x over previous
//
#include <hip/hip_runtime.h>
#include <hip/hip_bf16.h>
#include <hip/hip_fp16.h>

// GaussianSmoothing (2,1,192,192,192) f32, separable K=13 sigma=2.
// FINAL (R13 champion, reverted after R14/R15/R16 A/B regressions):
// Pass 1 blur_w : W-blur, 2 quads/thread (cached loads - lane-overlap reuse
//                 lives in L1/L2; NT loads regressed 33%), f32 x -> f16 tmp1
// Pass 2 colH   : H direct-form, CH=12, 24 upfront loads (deep MLP),
//                 f16 tmp1 -> f16 tmp2
// Pass 3 colD   : D direct-form, CH=12, NT f32 stores, f16 tmp2 -> f32 d_out

#define DIM 192
#define DIM2 (192 * 192)
#define NIMG 2
#define TOTAL (NIMG * DIM * DIM2)   // 14,155,776 floats
#define NQ (TOTAL / 4)              // 3,538,944 quads (4 elems, 48/row)
#define NPAIR (NQ / 2)              // 1,769,472 quad-pairs (24/row)

typedef float f32x4 __attribute__((ext_vector_type(4)));

#define GTAPS                                                     \
    constexpr float G[13] = {                                     \
        2.2159242e-03f, 8.7641505e-03f, 2.6995483e-02f,           \
        6.4758800e-02f, 1.2098536e-01f, 1.7603266e-01f,           \
        1.9947114e-01f, 1.7603266e-01f, 1.2098536e-01f,           \
        6.4758800e-02f, 2.6995483e-02f, 8.7641505e-03f,           \
        2.2159242e-03f };

// ---- f16 helpers ----------------------------------------------------------
__device__ __forceinline__ float4 ld_h4(const uint2* __restrict__ p) {
    uint2 u = *p;
    __half2 h0 = *(__half2*)&u.x;
    __half2 h1 = *(__half2*)&u.y;
    return make_float4(__low2float(h0), __high2float(h0),
                       __low2float(h1), __high2float(h1));
}
__device__ __forceinline__ uint2 st_h4(float4 v) {
    __half2 h0 = __floats2half2_rn(v.x, v.y);
    __half2 h1 = __floats2half2_rn(v.z, v.w);
    uint2 u;
    u.x = *(unsigned*)&h0;
    u.y = *(unsigned*)&h1;
    return u;
}

// ---------------------------------------------------------------------------
// Pass 1: W-blur, TWO quads (8 floats) per thread. Window = 6 quads
// [2jp-2 .. 2jp+3], clamped + 0/1-masked (branch-free). One 16B uint4 store
// of 8 f16 values. Grid = NPAIR/256 = 6912 blocks (13824 waves).
// ---------------------------------------------------------------------------
__global__ __launch_bounds__(256) void blur_w(const float4* __restrict__ in,
                                              uint4* __restrict__ out) {
    GTAPS
    const int j = blockIdx.x * 256 + threadIdx.x;   // pair id
    const int jp = j % 24;                          // pair within row
    const int rowq = (j / 24) * 48;                 // row base, quad units

    float f[24];
#pragma unroll
    for (int d = 0; d < 6; ++d) {
        int qq = 2 * jp - 2 + d;
        const float m = (qq >= 0 && qq < 48) ? 1.0f : 0.0f;
        qq = min(max(qq, 0), 47);
        float4 v = in[rowq + qq];
        if (d < 2 || d > 3) {                       // d=2,3 always valid
            v.x *= m; v.y *= m; v.z *= m; v.w *= m;
        }
        *(float4*)&f[d * 4] = v;
    }

    float o[8];
#pragma unroll
    for (int t = 0; t < 8; ++t) {
        float a = 0.0f;
#pragma unroll
        for (int k = 0; k < 13; ++k) a += G[k] * f[t + 2 + k];
        o[t] = a;
    }
    uint2 lo = st_h4(make_float4(o[0], o[1], o[2], o[3]));
    uint2 hi = st_h4(make_float4(o[4], o[5], o[6], o[7]));
    uint4 r; r.x = lo.x; r.y = lo.y; r.z = hi.x; r.w = hi.y;
    out[j] = r;
}

// ---------------------------------------------------------------------------
// Passes 2/3: DIRECT-FORM axis blur. Thread owns one f16-quad column (uint2),
// loads all CH+12=24 inputs upfront (deep MLP), then computes CH=12 outputs
// at 13 FMA/output. chunk is block-uniform; edge chunks use compile-time
// clipped bodies, interior has no masking.
//   column c: base = (c / Q) * M + (c % Q)   (quad units)
//   H: Q=48, M=9216, S=48     D: Q=9216, M=1769472, S=9216
// ncols = 18432; chunks = 16; block = 128 -> grid = 2304 (4608 waves).
// OUT_F32 (final pass) stores are NONTEMPORAL: no L3 allocation.
// ---------------------------------------------------------------------------
#define CH 12
#define NSTEP (CH + 12)     // 24
#define NCHUNK (DIM / CH)   // 16

template <int S, bool OUT_F32, int CLIP>
__device__ __forceinline__ void col_body(const uint2* __restrict__ in,
                                         void* __restrict__ out_,
                                         int base, int d0) {
    GTAPS
    float4 v[NSTEP];
#pragma unroll
    for (int s = 0; s < NSTEP; ++s) {
        bool valid = true;
        if (CLIP < 0) valid = (s >= 6);          // d0 == 0:   i = s-6
        if (CLIP > 0) valid = (s < NSTEP - 6);   // d0 == 180: i = 174+s
        if (valid) v[s] = ld_h4(&in[base + (d0 - 6 + s) * S]);
        else       v[s] = make_float4(0.f, 0.f, 0.f, 0.f);
    }
#pragma unroll
    for (int t = 0; t < CH; ++t) {
        float4 a = make_float4(0.f, 0.f, 0.f, 0.f);
#pragma unroll
        for (int k = 0; k < 13; ++k) {
            const float g = G[k];
            a.x += g * v[t + k].x;
            a.y += g * v[t + k].y;
            a.z += g * v[t + k].z;
            a.w += g * v[t + k].w;
        }
        const int o = base + (d0 + t) * S;
        if (OUT_F32) {
            f32x4 av;
            av.x = a.x; av.y = a.y; av.z = a.z; av.w = a.w;
            __builtin_nontemporal_store(av, &((f32x4*)out_)[o]);
        } else {
            ((uint2*)out_)[o] = st_h4(a);
        }
    }
}

template <int Q, int M, int S, bool OUT_F32>
__global__ __launch_bounds__(128) void col_blur(const uint2* __restrict__ in,
                                                void* __restrict__ out_) {
    const int gt = blockIdx.x * 128 + threadIdx.x;
    const int chunk = gt / 18432;          // block-uniform (18432 % 128 == 0)
    const int c = gt % 18432;
    const int base = (c / Q) * M + (c % Q);
    const int d0 = chunk * CH;

    if (chunk == 0)                col_body<S, OUT_F32, -1>(in, out_, base, d0);
    else if (chunk == NCHUNK - 1)  col_body<S, OUT_F32, +1>(in, out_, base, d0);
    else                           col_body<S, OUT_F32,  0>(in, out_, base, d0);
}

extern "C" void kernel_launch(void* const* d_in, const int* in_sizes, int n_in,
                              void* d_out, int out_size, void* d_ws, size_t ws_size,
                              hipStream_t stream) {
    const float* x = (const float*)d_in[0];
    float* out = (float*)d_out;
    uint2* tmp1 = (uint2*)d_ws;               // f16, 28.3 MB (NQ uint2)
    uint2* tmp2 = ((uint2*)d_ws) + NQ;        // f16, 28.3 MB

    // Pass 1: W one-shot (2 quads/thread), f32 x -> f16 tmp1
    blur_w<<<NPAIR / 256, 256, 0, stream>>>((const float4*)x, (uint4*)tmp1);
    // Pass 2: H axis (stride 48 quads), f16 -> f16, direct form
    col_blur<48, 9216, 48, false><<<2304, 128, 0, stream>>>(tmp1, (void*)tmp2);
    // Pass 3: D axis (stride 9216 quads), f16 -> f32 out, direct form, NT stores
    col_blur<9216, 1769472, 9216, true><<<2304, 128, 0, stream>>>(tmp2, (void*)out);
}